// Round 8
// baseline (233.205 us; speedup 1.0000x reference)
//
#include <hip/hip_runtime.h>
#include <math.h>

// Problem constants
#define Bn   4
#define Cc   64
#define Hh   128
#define Ww   128
#define Oo   64
#define HW   16384
#define CIN  128
#define KK   9
#define NPAR 27

// Workspace layout (float offsets)
#define WB2_OFF 0        // bf16 W2[32][1152] K-permuted = 18432 float slots
#define WB_OFF  18432    // bf16 W [64][576]  K-permuted = 18432 float slots

typedef __attribute__((ext_vector_type(8))) short bf16x8;
typedef __attribute__((ext_vector_type(4))) float f32x4;
typedef __attribute__((ext_vector_type(2), aligned(4))) float f32x2u;  // 4B-aligned pair

__device__ __forceinline__ short f2bf(float f) {
    unsigned u = __builtin_bit_cast(unsigned, f);
    u += 0x7FFFu + ((u >> 16) & 1u);        // RNE
    return (short)(u >> 16);
}

// ---------------------------------------------------------------------------
// Prepass: bf16 weights in PERMUTED K order. K position p = g*8+j with
// t = g%9 (tap, constant within the 8-group), c = (g/9)*8+j (8 consecutive
// channels): one tap-param read per 8 B-values, channel-major plane sweep.
//   wb2[j_out][p] <- {w_off|w_mod}[j_out][c][t]  (j_out 27..31 = 0)
//   wb [o][p]     <- w_reg[o][c][t]
// ---------------------------------------------------------------------------
__global__ void prep_weights(const float* __restrict__ w_off,
                             const float* __restrict__ w_mod,
                             const float* __restrict__ w_reg,
                             float* __restrict__ ws) {
    int i = blockIdx.x * 256 + threadIdx.x;
    short* wb2 = (short*)(ws + WB2_OFF);
    short* wb  = (short*)(ws + WB_OFF);
    if (i < 32 * 1152) {
        int j_out = i / 1152, r = i - j_out * 1152;
        int g = r >> 3, jj = r & 7;
        int t = g % 9, c = (g / 9) * 8 + jj;
        int k = c * 9 + t;
        float v = 0.f;
        if (j_out < 18)      v = w_off[j_out * 1152 + k];
        else if (j_out < 27) v = w_mod[(j_out - 18) * 1152 + k];
        wb2[i] = f2bf(v);
    }
    if (i < 64 * 576) {
        int o = i / 576, r = i - o * 576;
        int g = r >> 3, jj = r & 7;
        int t = g % 9, c = (g / 9) * 8 + jj;
        wb[i] = f2bf(w_reg[o * 576 + c * 9 + t]);
    }
}

// ---------------------------------------------------------------------------
// fused kernel (R7 structure + R8 scheduling changes):
//  - __launch_bounds__(256,6): 6 blocks/CU (24KB LDS x6 = 144KB), more TLP.
//  - both MFMA loops FULLY UNROLLED: compiler pipelines step s+1 gathers
//    under step s compute (was serialized by the dynamic loop).
// Layouts (m89/m120): A[m=lane&15][k=quad*8+j], B[k=quad*8+j][n=lane&15],
// D[row=quad*4+reg][col=lane&15].
// ---------------------------------------------------------------------------
#define PSTR 66   // sPar stride (64+2)
#define ISTR 65   // sIdx/sWt stride

__global__ __launch_bounds__(256, 6)
void fused_dcn(const float* __restrict__ x, const float* __restrict__ g,
               const float* __restrict__ ws_,
               const float* __restrict__ b_off, const float* __restrict__ b_mod,
               float* __restrict__ out) {
    __shared__ float  sPar[27 * PSTR];
    __shared__ int    sOffC[9 * 68];
    __shared__ int2   sIdx[9 * ISTR];
    __shared__ float4 sWt [9 * ISTR];

    const int tid = threadIdx.x;
    const int l = tid & 63, lm = l & 15, quad = l >> 4;
    const int w = __builtin_amdgcn_readfirstlane(tid >> 6);
    const int b = blockIdx.z;
    const int ho0 = blockIdx.y * 4, wo0 = blockIdx.x * 16;
    const int px = (w << 4) + lm;
    const int ho = ho0 + w, wo = wo0 + lm;

    const short* wb2 = (const short*)(ws_ + WB2_OFF);
    const short* wbp = (const short*)(ws_ + WB_OFF);
    const float* xb = x + ((size_t)(b * Cc) << 14);
    const float* gb = g + ((size_t)(b * Cc) << 14);

    // --- conv tap-offset table: off = valid ? (y<<7)+x : -1 ---------------
    for (int s = tid; s < 9 * 64; s += 256) {
        int t = s >> 6, sl = s & 63;
        int dy = t / 3, dx = t - dy * 3;
        int y = ho0 + (sl >> 4) + dy - 1;
        int xx = wo0 + (sl & 15) + dx - 1;
        bool ok = ((unsigned)y < 128u) && ((unsigned)xx < 128u);
        sOffC[t * 68 + sl] = ok ? ((y << 7) + xx) : -1;
    }
    __syncthreads();

    // --- Part 1: conv MFMA (K=1152 permuted, 36 steps, FULL UNROLL) -------
    f32x4 acc0 = {0.f, 0.f, 0.f, 0.f}, acc1 = {0.f, 0.f, 0.f, 0.f};
#pragma unroll
    for (int s = 0; s < 36; s++) {
        int gg = s * 4 + quad;
        int cb = (gg * 7282) >> 16;               // gg/9
        int t  = gg - 9 * cb;
        int off = sOffC[t * 68 + px];
        const float* basep = (cb < 8 ? xb : gb) + ((size_t)((cb & 7) * 8) << 14);
        int offc = off < 0 ? 0 : off;
        union { short s[8]; bf16x8 v; } u;
#pragma unroll
        for (int j = 0; j < 8; j++) {
            float val = basep[((size_t)j << 14) + offc];
            u.s[j] = f2bf(off < 0 ? 0.f : val);
        }
        const short* arow = wb2 + s * 32 + quad * 8;
        bf16x8 a0 = *(const bf16x8*)(arow + lm * 1152);
        bf16x8 a1 = *(const bf16x8*)(arow + (16 + lm) * 1152);
        acc0 = __builtin_amdgcn_mfma_f32_16x16x32_bf16(a0, u.v, acc0, 0, 0, 0);
        acc1 = __builtin_amdgcn_mfma_f32_16x16x32_bf16(a1, u.v, acc1, 0, 0, 0);
    }

    // --- conv epilogue -> sPar (LDS) --------------------------------------
#pragma unroll
    for (int mt = 0; mt < 2; mt++) {
        f32x4 a = mt ? acc1 : acc0;
#pragma unroll
        for (int reg = 0; reg < 4; reg++) {
            int j = mt * 16 + quad * 4 + reg;
            float v = a[reg];
            if (j < 18) {
                int k = j >> 1;
                float vb = v + b_off[j];
                if (j & 1) sPar[(9 + k) * PSTR + px] = vb + (float)(k - (k / 3) * 3 + wo - 1);
                else       sPar[k * PSTR + px]       = vb + (float)(k / 3 + ho - 1);
            } else if (j < 27) {
                int k = j - 18;
                sPar[(18 + k) * PSTR + px] = 2.f / (1.f + __expf(-(v + b_mod[k])));
            }
        }
    }
    __syncthreads();

    // --- stage A: bilinear pair-folded params from sPar -------------------
    for (int s = tid; s < 9 * 64; s += 256) {
        int k = s >> 6, sl = s & 63;
        float py = sPar[k * PSTR + sl];
        float pxx = sPar[(9 + k) * PSTR + sl];
        float m  = sPar[(18 + k) * PSTR + sl];
        float fy = floorf(py), fx = floorf(pxx);
        int y0 = (int)fy, x0 = (int)fx;
        int y1 = y0 + 1;
        float wy1 = py - fy, wx1 = pxx - fx;
        float wy0 = 1.f - wy1, wx0 = 1.f - wx1;
        bool vy0 = (unsigned)y0 < 128u, vy1 = (unsigned)y1 < 128u;
        bool vx0 = (unsigned)x0 < 128u, vx1 = (unsigned)(x0 + 1) < 128u;
        int cy0 = min(max(y0, 0), 127), cy1 = min(max(y1, 0), 127);
        int bx2 = min(max(x0, 0), 126);
        bool sel_lo = (x0 < 0), sel_hi = (x0 > 126);
        float w00 = (vy0 && vx0) ? wy0 * wx0 * m : 0.f;
        float w01 = (vy0 && vx1) ? wy0 * wx1 * m : 0.f;
        float w10 = (vy1 && vx0) ? wy1 * wx0 * m : 0.f;
        float w11 = (vy1 && vx1) ? wy1 * wx1 * m : 0.f;
        float wa0 = sel_lo ? w01 : (sel_hi ? 0.f : w00);
        float wb0 = sel_hi ? w00 : (sel_lo ? 0.f : w01);
        float wa1 = sel_lo ? w11 : (sel_hi ? 0.f : w10);
        float wb1 = sel_hi ? w10 : (sel_lo ? 0.f : w11);
        sIdx[k * ISTR + sl] = make_int2((cy0 << 7) + bx2, (cy1 << 7) + bx2);
        sWt [k * ISTR + sl] = make_float4(wa0, wb0, wa1, wb1);
    }
    __syncthreads();

    // --- Part 2: deform MFMA (K=576 permuted, 18 steps, FULL UNROLL) ------
    f32x4 acc[4];
#pragma unroll
    for (int mt = 0; mt < 4; mt++) acc[mt] = (f32x4){0.f, 0.f, 0.f, 0.f};

#pragma unroll
    for (int s = 0; s < 18; s++) {
        int gg = s * 4 + quad;                    // 0..71
        int cb = (gg * 7282) >> 16;               // gg/9 (0..7)
        int t  = gg - 9 * cb;
        int2   id = sIdx[t * ISTR + px];
        float4 wv = sWt [t * ISTR + px];
        const float* basep = xb + ((size_t)(cb * 8) << 14);
        union { short s[8]; bf16x8 v; } u;
#pragma unroll
        for (int j = 0; j < 8; j++) {
            const float* xq = basep + ((size_t)j << 14);
            f32x2u p0 = *(const f32x2u*)(xq + id.x);
            f32x2u p1 = *(const f32x2u*)(xq + id.y);
            u.s[j] = f2bf(wv.x * p0.x + wv.y * p0.y + wv.z * p1.x + wv.w * p1.y);
        }
        const short* arow = wbp + s * 32 + quad * 8;
#pragma unroll
        for (int mt = 0; mt < 4; mt++) {
            bf16x8 a = *(const bf16x8*)(arow + (mt * 16 + lm) * 576);
            acc[mt] = __builtin_amdgcn_mfma_f32_16x16x32_bf16(a, u.v, acc[mt], 0, 0, 0);
        }
    }

    // --- store ------------------------------------------------------------
    const int pix = (ho << 7) + wo;
#pragma unroll
    for (int mt = 0; mt < 4; mt++) {
        float* op = out + ((size_t)(b * Oo + mt * 16 + quad * 4) << 14) + pix;
#pragma unroll
        for (int reg = 0; reg < 4; reg++)
            op[(size_t)reg << 14] = acc[mt][reg];
    }
}

// ---------------------------------------------------------------------------
extern "C" void kernel_launch(void* const* d_in, const int* in_sizes, int n_in,
                              void* d_out, int out_size, void* d_ws, size_t ws_size,
                              hipStream_t stream) {
    const float* x     = (const float*)d_in[0];
    const float* guide = (const float*)d_in[1];
    const float* w_off = (const float*)d_in[2];
    const float* b_off = (const float*)d_in[3];
    const float* w_mod = (const float*)d_in[4];
    const float* b_mod = (const float*)d_in[5];
    const float* w_reg = (const float*)d_in[6];
    float* out = (float*)d_out;
    float* ws  = (float*)d_ws;

    hipLaunchKernelGGL(prep_weights, dim3((32 * 1152 + 255) / 256), dim3(256),
                       0, stream, w_off, w_mod, w_reg, ws);
    hipLaunchKernelGGL(fused_dcn, dim3(Ww / 16, Hh / 4, Bn), dim3(256),
                       0, stream, x, guide, ws, b_off, b_mod, out);
}

// Round 9
// 220.824 us; speedup vs baseline: 1.0561x; 1.0561x over previous
//
#include <hip/hip_runtime.h>
#include <math.h>

// Problem constants
#define Bn   4
#define Cc   64
#define Hh   128
#define Ww   128
#define Oo   64
#define HW   16384
#define CIN  128
#define KK   9
#define NPAR 27

// Workspace layout (float offsets)
#define WB2_OFF 0        // bf16 W2[32][1152] K-permuted = 18432 float slots
#define WB_OFF  18432    // bf16 W [64][576]  K-permuted = 18432 float slots

typedef __attribute__((ext_vector_type(8))) short bf16x8;
typedef __attribute__((ext_vector_type(4))) float f32x4;
typedef __attribute__((ext_vector_type(2), aligned(4))) float f32x2u;  // 4B-aligned pair

__device__ __forceinline__ short f2bf(float f) {
    unsigned u = __builtin_bit_cast(unsigned, f);
    u += 0x7FFFu + ((u >> 16) & 1u);        // RNE
    return (short)(u >> 16);
}

// ---------------------------------------------------------------------------
// Prepass: bf16 weights in PERMUTED K order. K position p = g*8+j with
// t = g%9 (tap, constant within the 8-group), c = (g/9)*8+j (8 consecutive
// channels): one tap-param read per 8 B-values, channel-major plane sweep.
//   wb2[j_out][p] <- {w_off|w_mod}[j_out][c][t]  (j_out 27..31 = 0)
//   wb [o][p]     <- w_reg[o][c][t]
// ---------------------------------------------------------------------------
__global__ void prep_weights(const float* __restrict__ w_off,
                             const float* __restrict__ w_mod,
                             const float* __restrict__ w_reg,
                             float* __restrict__ ws) {
    int i = blockIdx.x * 256 + threadIdx.x;
    short* wb2 = (short*)(ws + WB2_OFF);
    short* wb  = (short*)(ws + WB_OFF);
    if (i < 32 * 1152) {
        int j_out = i / 1152, r = i - j_out * 1152;
        int g = r >> 3, jj = r & 7;
        int t = g % 9, c = (g / 9) * 8 + jj;
        int k = c * 9 + t;
        float v = 0.f;
        if (j_out < 18)      v = w_off[j_out * 1152 + k];
        else if (j_out < 27) v = w_mod[(j_out - 18) * 1152 + k];
        wb2[i] = f2bf(v);
    }
    if (i < 64 * 576) {
        int o = i / 576, r = i - o * 576;
        int g = r >> 3, jj = r & 7;
        int t = g % 9, c = (g / 9) * 8 + jj;
        wb[i] = f2bf(w_reg[o * 576 + c * 9 + t]);
    }
}

// ---------------------------------------------------------------------------
// fused kernel (R7 structure; R9: launch_bounds(256,6) for 6 blocks/CU TLP,
// MFMA s-loops unrolled x2 ONLY (R8's full unroll spilled to scratch:
// WRITE_SIZE 16->94MB — do not full-unroll these loops).
// Layouts (m89/m120): A[m=lane&15][k=quad*8+j], B[k=quad*8+j][n=lane&15],
// D[row=quad*4+reg][col=lane&15].
// ---------------------------------------------------------------------------
#define PSTR 66   // sPar stride (64+2)
#define ISTR 65   // sIdx/sWt stride

__global__ __launch_bounds__(256, 6)
void fused_dcn(const float* __restrict__ x, const float* __restrict__ g,
               const float* __restrict__ ws_,
               const float* __restrict__ b_off, const float* __restrict__ b_mod,
               float* __restrict__ out) {
    __shared__ float  sPar[27 * PSTR];
    __shared__ int    sOffC[9 * 68];
    __shared__ int2   sIdx[9 * ISTR];
    __shared__ float4 sWt [9 * ISTR];

    const int tid = threadIdx.x;
    const int l = tid & 63, lm = l & 15, quad = l >> 4;
    const int w = __builtin_amdgcn_readfirstlane(tid >> 6);
    const int b = blockIdx.z;
    const int ho0 = blockIdx.y * 4, wo0 = blockIdx.x * 16;
    const int px = (w << 4) + lm;
    const int ho = ho0 + w, wo = wo0 + lm;

    const short* wb2 = (const short*)(ws_ + WB2_OFF);
    const short* wbp = (const short*)(ws_ + WB_OFF);
    const float* xb = x + ((size_t)(b * Cc) << 14);
    const float* gb = g + ((size_t)(b * Cc) << 14);

    // --- conv tap-offset table: off = valid ? (y<<7)+x : -1 ---------------
    for (int s = tid; s < 9 * 64; s += 256) {
        int t = s >> 6, sl = s & 63;
        int dy = t / 3, dx = t - dy * 3;
        int y = ho0 + (sl >> 4) + dy - 1;
        int xx = wo0 + (sl & 15) + dx - 1;
        bool ok = ((unsigned)y < 128u) && ((unsigned)xx < 128u);
        sOffC[t * 68 + sl] = ok ? ((y << 7) + xx) : -1;
    }
    __syncthreads();

    // --- Part 1: conv MFMA (K=1152 permuted, 36 steps, unroll x2) ---------
    f32x4 acc0 = {0.f, 0.f, 0.f, 0.f}, acc1 = {0.f, 0.f, 0.f, 0.f};
#pragma unroll 2
    for (int s = 0; s < 36; s++) {
        int gg = s * 4 + quad;
        int cb = (gg * 7282) >> 16;               // gg/9
        int t  = gg - 9 * cb;
        int off = sOffC[t * 68 + px];
        const float* basep = (cb < 8 ? xb : gb) + ((size_t)((cb & 7) * 8) << 14);
        int offc = off < 0 ? 0 : off;
        union { short s[8]; bf16x8 v; } u;
#pragma unroll
        for (int j = 0; j < 8; j++) {
            float val = basep[((size_t)j << 14) + offc];
            u.s[j] = f2bf(off < 0 ? 0.f : val);
        }
        const short* arow = wb2 + s * 32 + quad * 8;
        bf16x8 a0 = *(const bf16x8*)(arow + lm * 1152);
        bf16x8 a1 = *(const bf16x8*)(arow + (16 + lm) * 1152);
        acc0 = __builtin_amdgcn_mfma_f32_16x16x32_bf16(a0, u.v, acc0, 0, 0, 0);
        acc1 = __builtin_amdgcn_mfma_f32_16x16x32_bf16(a1, u.v, acc1, 0, 0, 0);
    }

    // --- conv epilogue -> sPar (LDS) --------------------------------------
#pragma unroll
    for (int mt = 0; mt < 2; mt++) {
        f32x4 a = mt ? acc1 : acc0;
#pragma unroll
        for (int reg = 0; reg < 4; reg++) {
            int j = mt * 16 + quad * 4 + reg;
            float v = a[reg];
            if (j < 18) {
                int k = j >> 1;
                float vb = v + b_off[j];
                if (j & 1) sPar[(9 + k) * PSTR + px] = vb + (float)(k - (k / 3) * 3 + wo - 1);
                else       sPar[k * PSTR + px]       = vb + (float)(k / 3 + ho - 1);
            } else if (j < 27) {
                int k = j - 18;
                sPar[(18 + k) * PSTR + px] = 2.f / (1.f + __expf(-(v + b_mod[k])));
            }
        }
    }
    __syncthreads();

    // --- stage A: bilinear pair-folded params from sPar -------------------
    for (int s = tid; s < 9 * 64; s += 256) {
        int k = s >> 6, sl = s & 63;
        float py = sPar[k * PSTR + sl];
        float pxx = sPar[(9 + k) * PSTR + sl];
        float m  = sPar[(18 + k) * PSTR + sl];
        float fy = floorf(py), fx = floorf(pxx);
        int y0 = (int)fy, x0 = (int)fx;
        int y1 = y0 + 1;
        float wy1 = py - fy, wx1 = pxx - fx;
        float wy0 = 1.f - wy1, wx0 = 1.f - wx1;
        bool vy0 = (unsigned)y0 < 128u, vy1 = (unsigned)y1 < 128u;
        bool vx0 = (unsigned)x0 < 128u, vx1 = (unsigned)(x0 + 1) < 128u;
        int cy0 = min(max(y0, 0), 127), cy1 = min(max(y1, 0), 127);
        int bx2 = min(max(x0, 0), 126);
        bool sel_lo = (x0 < 0), sel_hi = (x0 > 126);
        float w00 = (vy0 && vx0) ? wy0 * wx0 * m : 0.f;
        float w01 = (vy0 && vx1) ? wy0 * wx1 * m : 0.f;
        float w10 = (vy1 && vx0) ? wy1 * wx0 * m : 0.f;
        float w11 = (vy1 && vx1) ? wy1 * wx1 * m : 0.f;
        float wa0 = sel_lo ? w01 : (sel_hi ? 0.f : w00);
        float wb0 = sel_hi ? w00 : (sel_lo ? 0.f : w01);
        float wa1 = sel_lo ? w11 : (sel_hi ? 0.f : w10);
        float wb1 = sel_hi ? w10 : (sel_lo ? 0.f : w11);
        sIdx[k * ISTR + sl] = make_int2((cy0 << 7) + bx2, (cy1 << 7) + bx2);
        sWt [k * ISTR + sl] = make_float4(wa0, wb0, wa1, wb1);
    }
    __syncthreads();

    // --- Part 2: deform MFMA (K=576 permuted, 18 steps, unroll x2) --------
    f32x4 acc[4];
#pragma unroll
    for (int mt = 0; mt < 4; mt++) acc[mt] = (f32x4){0.f, 0.f, 0.f, 0.f};

#pragma unroll 2
    for (int s = 0; s < 18; s++) {
        int gg = s * 4 + quad;                    // 0..71
        int cb = (gg * 7282) >> 16;               // gg/9 (0..7)
        int t  = gg - 9 * cb;
        int2   id = sIdx[t * ISTR + px];
        float4 wv = sWt [t * ISTR + px];
        const float* basep = xb + ((size_t)(cb * 8) << 14);
        union { short s[8]; bf16x8 v; } u;
#pragma unroll
        for (int j = 0; j < 8; j++) {
            const float* xq = basep + ((size_t)j << 14);
            f32x2u p0 = *(const f32x2u*)(xq + id.x);
            f32x2u p1 = *(const f32x2u*)(xq + id.y);
            u.s[j] = f2bf(wv.x * p0.x + wv.y * p0.y + wv.z * p1.x + wv.w * p1.y);
        }
        const short* arow = wbp + s * 32 + quad * 8;
#pragma unroll
        for (int mt = 0; mt < 4; mt++) {
            bf16x8 a = *(const bf16x8*)(arow + (mt * 16 + lm) * 576);
            acc[mt] = __builtin_amdgcn_mfma_f32_16x16x32_bf16(a, u.v, acc[mt], 0, 0, 0);
        }
    }

    // --- store ------------------------------------------------------------
    const int pix = (ho << 7) + wo;
#pragma unroll
    for (int mt = 0; mt < 4; mt++) {
        float* op = out + ((size_t)(b * Oo + mt * 16 + quad * 4) << 14) + pix;
#pragma unroll
        for (int reg = 0; reg < 4; reg++)
            op[(size_t)reg << 14] = acc[mt][reg];
    }
}

// ---------------------------------------------------------------------------
extern "C" void kernel_launch(void* const* d_in, const int* in_sizes, int n_in,
                              void* d_out, int out_size, void* d_ws, size_t ws_size,
                              hipStream_t stream) {
    const float* x     = (const float*)d_in[0];
    const float* guide = (const float*)d_in[1];
    const float* w_off = (const float*)d_in[2];
    const float* b_off = (const float*)d_in[3];
    const float* w_mod = (const float*)d_in[4];
    const float* b_mod = (const float*)d_in[5];
    const float* w_reg = (const float*)d_in[6];
    float* out = (float*)d_out;
    float* ws  = (float*)d_ws;

    hipLaunchKernelGGL(prep_weights, dim3((32 * 1152 + 255) / 256), dim3(256),
                       0, stream, w_off, w_mod, w_reg, ws);
    hipLaunchKernelGGL(fused_dcn, dim3(Ww / 16, Hh / 4, Bn), dim3(256),
                       0, stream, x, guide, ws, b_off, b_mod, out);
}